// Round 15
// baseline (776.967 us; speedup 1.0000x reference)
//
#include <hip/hip_runtime.h>
#include <hip/hip_bf16.h>
#include <math.h>

#define B_   4
#define L_   512
#define H_   768
#define NH_  12
#define HD_  64
#define M_   3072
#define NL_  6
#define RD_  128
#define NR_  255          // 2*RD-1
#define ROWS (B_*L_)      // 2048
#define MEXT 2304         // ROWS + NR_ + 1 pad (merged QKV+rel output rows)
#define COEF_ 0.125f      // 1/sqrt(64)

typedef __attribute__((ext_vector_type(8))) short bf16x8;
typedef __attribute__((ext_vector_type(4))) float f32x4;

// ---------------- utility ----------------

static __device__ __forceinline__ float wave_reduce_sum(float v) {
#pragma unroll
    for (int off = 32; off > 0; off >>= 1) v += __shfl_xor(v, off, 64);
    return v;
}

static __device__ __forceinline__ float gelu_f(float x) {
    float x3 = x * x * x;
    return 0.5f * x * (1.f + tanhf(0.7978845608028654f * (x + 0.044715f * x3)));
}

static __device__ __forceinline__ unsigned short f2bfu(float v) {
    __hip_bfloat16 h = __float2bfloat16(v);
    return *(unsigned short*)&h;
}

static __device__ __forceinline__ float bfu2f(unsigned short u) {
    union { float f; unsigned int i; } x;
    x.i = ((unsigned int)u) << 16;
    return x.f;
}

// async global->LDS, 16B per lane; LDS dest = wave-uniform base + lane*16
static __device__ __forceinline__ void gload16(const void* g, void* l) {
    __builtin_amdgcn_global_load_lds(
        (const __attribute__((address_space(1))) void*)g,
        (__attribute__((address_space(3))) void*)l,
        16, 0, 0);
}

// ---------------- embedding + LN (fp32 out + bf16 twin) ----------------

__global__ __launch_bounds__(256) void embed_ln_kernel(
    const int* __restrict__ tok, const int* __restrict__ seg,
    const float* __restrict__ temb, const float* __restrict__ semb,
    const float* __restrict__ sc, const float* __restrict__ bi,
    float* __restrict__ out, __hip_bfloat16* __restrict__ outb)
{
    int row = blockIdx.x;
    int t = threadIdx.x;
    int tid = tok[row], sid = seg[row];
    const float* tp = temb + (size_t)tid * H_;
    const float* sp = semb + (size_t)sid * H_;
    float v[3];
#pragma unroll
    for (int j = 0; j < 3; j++) { int idx = t + j * 256; v[j] = tp[idx] + sp[idx]; }

    __shared__ float red[4];
    __shared__ float bc;
    int lane = t & 63, wid = t >> 6;

    float s = v[0] + v[1] + v[2];
    s = wave_reduce_sum(s);
    if (lane == 0) red[wid] = s;
    __syncthreads();
    if (t == 0) bc = (red[0] + red[1] + red[2] + red[3]) * (1.f / H_);
    __syncthreads();
    float mean = bc;

    float c[3]; float ss = 0.f;
#pragma unroll
    for (int j = 0; j < 3; j++) { c[j] = v[j] - mean; ss += c[j] * c[j]; }
    ss = wave_reduce_sum(ss);
    __syncthreads();
    if (lane == 0) red[wid] = ss;
    __syncthreads();
    if (t == 0) bc = rsqrtf((red[0] + red[1] + red[2] + red[3]) * (1.f / H_) + 1e-12f);
    __syncthreads();
    float r = bc;
#pragma unroll
    for (int j = 0; j < 3; j++) {
        int idx = t + j * 256;
        float o = c[j] * r * sc[idx] + bi[idx];
        out[(size_t)row * H_ + idx] = o;
        outb[(size_t)row * H_ + idx] = __float2bfloat16(o);
    }
}

// ---------------- residual add (+partials +bias) + LN (fp32 out + optional bf16 twin) ----------------

__global__ __launch_bounds__(256) void add_ln_kernel(
    const float* __restrict__ x, const float* __restrict__ p0,
    const float* __restrict__ p1, const float* __restrict__ p2,
    const float* __restrict__ bias,
    const float* __restrict__ sc, const float* __restrict__ bi,
    float* __restrict__ out, __hip_bfloat16* __restrict__ outb)
{
    int row = blockIdx.x;
    int t = threadIdx.x;
    const float* xp = x + (size_t)row * H_;
    const float* q0 = p0 + (size_t)row * H_;
    const float* q1 = p1 ? p1 + (size_t)row * H_ : nullptr;
    const float* q2 = p2 ? p2 + (size_t)row * H_ : nullptr;
    float v[3];
#pragma unroll
    for (int j = 0; j < 3; j++) {
        int idx = t + j * 256;
        float a = xp[idx] + q0[idx];
        if (q1) a += q1[idx];
        if (q2) a += q2[idx];
        if (bias) a += bias[idx];
        v[j] = a;
    }

    __shared__ float red[4];
    __shared__ float bc;
    int lane = t & 63, wid = t >> 6;

    float s = v[0] + v[1] + v[2];
    s = wave_reduce_sum(s);
    if (lane == 0) red[wid] = s;
    __syncthreads();
    if (t == 0) bc = (red[0] + red[1] + red[2] + red[3]) * (1.f / H_);
    __syncthreads();
    float mean = bc;

    float c[3]; float ss = 0.f;
#pragma unroll
    for (int j = 0; j < 3; j++) { c[j] = v[j] - mean; ss += c[j] * c[j]; }
    ss = wave_reduce_sum(ss);
    __syncthreads();
    if (lane == 0) red[wid] = ss;
    __syncthreads();
    if (t == 0) bc = rsqrtf((red[0] + red[1] + red[2] + red[3]) * (1.f / H_) + 1e-12f);
    __syncthreads();
    float r = bc;
#pragma unroll
    for (int j = 0; j < 3; j++) {
        int idx = t + j * 256;
        float o = c[j] * r * sc[idx] + bi[idx];
        out[(size_t)row * H_ + idx] = o;
        if (outb) outb[(size_t)row * H_ + idx] = __float2bfloat16(o);
    }
}

// ---------------- per-layer weight/bias/rel pack (round-8 form) ----------------

__global__ __launch_bounds__(256) void pack_layer_kernel(
    const float* __restrict__ wq, const float* __restrict__ wk, const float* __restrict__ wv,
    const float* __restrict__ wo, const float* __restrict__ w1, const float* __restrict__ w2,
    const float* __restrict__ bqL, const float* __restrict__ bkL, const float* __restrict__ bvL,
    const float* __restrict__ relL,
    __hip_bfloat16* __restrict__ WtQ, __hip_bfloat16* __restrict__ WtO,
    __hip_bfloat16* __restrict__ WtW1, __hip_bfloat16* __restrict__ WtW2,
    float* __restrict__ qkvbias, __hip_bfloat16* __restrict__ relb)
{
    const int z = blockIdx.z;
    const int t = threadIdx.x;
    if (z == 6) {
        int id = blockIdx.y * 96 + blockIdx.x;
        if (id < 765) {
            int i = id * 256 + t;              // 765*256 = 195840 = 255*768 exactly
            relb[i] = __float2bfloat16(relL[i]);
        } else if (id < 774) {
            int i = (id - 765) * 256 + t;
            if (i < 2304)
                qkvbias[i] = i < 768 ? bqL[i] : (i < 1536 ? bkL[i - 768] : bvL[i - 1536]);
        }
        return;
    }
    const float* in; __hip_bfloat16* out; int K, N;
    int bx = blockIdx.x, by = blockIdx.y;
    if (z < 4) {
        if (bx >= 24) return;
        K = 768; N = 768;
        in = (z == 0) ? wq : (z == 1) ? wk : (z == 2) ? wv : wo;
        out = (z < 3) ? WtQ + (size_t)z * H_ * H_ : WtO;
    } else if (z == 4) {
        K = 768; N = 3072; in = w1; out = WtW1;
    } else {
        K = 3072; N = 768; in = w2; out = WtW2;
        int tmp = bx; bx = by; by = tmp;       // bx<24 (N), by<96 (K)
    }
    __shared__ float tile[32][33];
    int bX = bx * 32, bY = by * 32;
    int tx = t & 31, ty = t >> 5;
#pragma unroll
    for (int i = 0; i < 4; i++)
        tile[ty + 8 * i][tx] = in[(size_t)(bY + ty + 8 * i) * N + bX + tx];
    __syncthreads();
#pragma unroll
    for (int i = 0; i < 4; i++)
        out[(size_t)(bX + ty + 8 * i) * K + bY + tx] = __float2bfloat16(tile[tx][ty + 8 * i]);
}

// ---------------- fused V / VR transpose ----------------

__global__ __launch_bounds__(256) void transpose_vvr_kernel(
    const __hip_bfloat16* __restrict__ qkvb,
    __hip_bfloat16* __restrict__ vT, __hip_bfloat16* __restrict__ vrT)
{
    __shared__ unsigned short tile[64][72];
    const int bx = blockIdx.x;
    const int h  = blockIdx.y;
    const int t = threadIdx.x;
    const int r = t >> 2, c0 = (t & 3) * 16;
    if (bx < 32) {
        const int kb = bx * 64;
        const unsigned short* src = (const unsigned short*)qkvb + (size_t)(kb + r) * 2304 + 1536 + h * 64 + c0;
        *(uint4*)&tile[r][c0]     = *(const uint4*)src;
        *(uint4*)&tile[r][c0 + 8] = *(const uint4*)(src + 8);
        __syncthreads();
        unsigned short outv[16];
#pragma unroll
        for (int i = 0; i < 16; i++) outv[i] = tile[c0 + i][r];
        unsigned short* dst = (unsigned short*)vT +
            ((size_t)((kb >> 9) * NH_ + h) * 64 + r) * 512 + (kb & 511) + c0;
        *(uint4*)dst       = *(uint4*)&outv[0];
        *(uint4*)(dst + 8) = *(uint4*)&outv[8];
    } else {
        const int jb = (bx - 32) * 64;
        const int j = jb + r;
        if (j < NR_) {
            const unsigned short* src = (const unsigned short*)qkvb + (size_t)(2048 + j) * 2304 + 1536 + h * 64 + c0;
            *(uint4*)&tile[r][c0]     = *(const uint4*)src;
            *(uint4*)&tile[r][c0 + 8] = *(const uint4*)(src + 8);
        } else {
#pragma unroll
            for (int i = 0; i < 16; i++) tile[r][c0 + i] = 0;
        }
        __syncthreads();
        unsigned short outv[16];
#pragma unroll
        for (int i = 0; i < 16; i++) outv[i] = tile[c0 + i][r];
        unsigned short* dst = (unsigned short*)vrT + ((size_t)(h * 64) + r) * 256 + jb + c0;
        *(uint4*)dst       = *(uint4*)&outv[0];
        *(uint4*)(dst + 8) = *(uint4*)&outv[8];
    }
}

// ---------------- bf16 MFMA GEMM: 128x64 tile, 8 waves, 2-phase dbuf (round-8 proven) ----------------
// A2 (optional): rows >= 2048 read from A2 (rel embedding rows, clamped to 254).

#define TK 64

__global__ __launch_bounds__(512, 6) void gemm_bf16_kernel(
    const __hip_bfloat16* __restrict__ A, const __hip_bfloat16* __restrict__ A2,
    const __hip_bfloat16* __restrict__ Bt,
    const float* __restrict__ bias, float* __restrict__ Cf, __hip_bfloat16* __restrict__ Cb,
    float* __restrict__ CfX, size_t xstride,
    int M, int N, int K, int act, int ksplit)
{
    __shared__ __hip_bfloat16 As[2][128 * TK];
    __shared__ __hip_bfloat16 Bs[2][64 * TK];
    const int t = threadIdx.x;
    const int lane = t & 63;
    const int wid = t >> 6;                 // 0..7
    const int lq = lane & 15, lg = lane >> 4;
    const int wm = (wid & 3) * 32, wn = (wid >> 2) * 32;

    const int nbx = gridDim.x;
    const int nwg = nbx * gridDim.y;
    int wgid = blockIdx.y * nbx + blockIdx.x;
    if ((nwg & 7) == 0) { int qq = nwg >> 3; wgid = (wgid & 7) * qq + (wgid >> 3); }
    const int bm = (wgid / nbx) * 128, bn = (wgid % nbx) * 64;
    const int kbase = blockIdx.z * ksplit;

    f32x4 acc[2][2];
#pragma unroll
    for (int i = 0; i < 2; i++)
#pragma unroll
        for (int j = 0; j < 2; j++) acc[i][j] = (f32x4){0.f, 0.f, 0.f, 0.f};

    const int rl = t >> 3;                              // 0..63
    const int cswz = (((t & 7) * 16) ^ ((rl & 7) << 4)) >> 1;   // elements
    const __hip_bfloat16* ga[2];
    const __hip_bfloat16* gb;
    int lofsA[2], lofsB;
#pragma unroll
    for (int c = 0; c < 2; c++) {
        int rowa = bm + c * 64 + rl;
        const __hip_bfloat16* base;
        if (A2 && rowa >= ROWS) {
            int rr = rowa - ROWS; if (rr > NR_ - 1) rr = NR_ - 1;
            base = A2 + (size_t)rr * K;
        } else {
            if (rowa >= M) rowa = M - 1;
            base = A + (size_t)rowa * K;
        }
        ga[c] = base + kbase + cswz;
        lofsA[c] = (c * 64 + wid * 8) * TK;
    }
    gb = Bt + (size_t)(bn + rl) * K + kbase + cswz;
    lofsB = (wid * 8) * TK;

    const int nt = ksplit / TK;
    gload16(ga[0], &As[0][lofsA[0]]);
    gload16(ga[1], &As[0][lofsA[1]]);
    gload16(gb,    &Bs[0][lofsB]);
    __syncthreads();

    int cur = 0;
    for (int kt = 0; kt < nt; kt++) {
        if (kt + 1 < nt) {
            const int koff = (kt + 1) * TK;
            gload16(ga[0] + koff, &As[cur ^ 1][lofsA[0]]);
            gload16(ga[1] + koff, &As[cur ^ 1][lofsA[1]]);
            gload16(gb + koff,    &Bs[cur ^ 1][lofsB]);
        }
#pragma unroll
        for (int kh = 0; kh < 2; kh++) {
            const int kb = kh * 64 + lg * 16;
            bf16x8 af[2], bfr[2];
#pragma unroll
            for (int i = 0; i < 2; i++) {
                int ra = wm + i * 16 + lq;
                af[i] = *(const bf16x8*)((const char*)&As[cur][0] + ra * 128 + (kb ^ ((ra & 7) << 4)));
            }
#pragma unroll
            for (int j = 0; j < 2; j++) {
                int rb = wn + j * 16 + lq;
                bfr[j] = *(const bf16x8*)((const char*)&Bs[cur][0] + rb * 128 + (kb ^ ((rb & 7) << 4)));
            }
#pragma unroll
            for (int i = 0; i < 2; i++)
#pragma unroll
                for (int j = 0; j < 2; j++)
                    acc[i][j] = __builtin_amdgcn_mfma_f32_16x16x32_bf16(af[i], bfr[j], acc[i][j], 0, 0, 0);
        }
        __syncthreads();
        cur ^= 1;
    }

    float* outf = (blockIdx.z == 0) ? Cf : (CfX + (size_t)(blockIdx.z - 1) * xstride);
#pragma unroll
    for (int i = 0; i < 2; i++) {
#pragma unroll
        for (int j = 0; j < 2; j++) {
            int col = bn + wn + j * 16 + lq;
            float bsv = bias ? bias[col] : 0.f;
            int row0 = bm + wm + i * 16 + lg * 4;
#pragma unroll
            for (int rr = 0; rr < 4; rr++) {
                int row = row0 + rr;
                if (row >= M) continue;
                float v = acc[i][j][rr] + bsv;
                if (act) v = gelu_f(v);
                if (Cb && blockIdx.z == 0) Cb[(size_t)row * N + col] = __float2bfloat16(v);
                else                       outf[(size_t)row * N + col] = v;
            }
        }
    }
}

// ---------------- MFMA rel-pos attention: merged R/S barrier + early PV prefetch ----------------

#define PS_LD 520   // bf16 elems per Ps row (512 + 8 pad)
#define PR_LD 264   // bf16 elems per Rq/prel row (256 + 8 pad)

__global__ __launch_bounds__(256, 3) void attn_kernel(
    const __hip_bfloat16* __restrict__ qkvb,  // [MEXT][2304]
    const __hip_bfloat16* __restrict__ vT,    // [B][NH][64][512]
    const __hip_bfloat16* __restrict__ vrT,   // [NH][64][256] (col 255 zero)
    const int* __restrict__ mask,
    __hip_bfloat16* __restrict__ ctxb)        // [2048][768]
{
    __shared__ unsigned short RqPrel[32 * PR_LD];
    __shared__ unsigned short Ps[32 * PS_LD];
    __shared__ float mstat[32 * 4];
    __shared__ float sstat[32 * 4];
    __shared__ float maskb[512];

    const int i_ = blockIdx.x;
    const int c_ = i_ & 7, s_ = i_ >> 3;
    const int p_ = c_ + 8 * (s_ >> 4);
    const int qt = s_ & 15;
    const int b = p_ / 12, h = p_ % 12;

    const int t = threadIdx.x;
    const int lane = t & 63, w = t >> 6;
    const int lq = lane & 15, lg = lane >> 4;

    maskb[t]       = mask[b * L_ + t]       ? 0.f : -1e30f;
    maskb[t + 256] = mask[b * L_ + t + 256] ? 0.f : -1e30f;

    const char* Qbase  = (const char*)qkvb + ((size_t)(b * L_ + qt * 32) * 2304 + h * 64) * 2;
    const char* Kbase  = (const char*)qkvb + ((size_t)(b * L_) * 2304 + 768 + h * 64) * 2;
    const char* KRbase = (const char*)qkvb + ((size_t)2048 * 2304 + 768 + h * 64) * 2;

    bf16x8 afq[2][2];
#pragma unroll
    for (int ks = 0; ks < 2; ks++) {
        const int kofs = ks * 64 + lg * 16;
        afq[ks][0] = *(const bf16x8*)(Qbase + (size_t)lq * 4608 + kofs);
        afq[ks][1] = *(const bf16x8*)(Qbase + (size_t)(16 + lq) * 4608 + kofs);
    }

    // ---- R phase ----
    f32x4 accr[2][4];
#pragma unroll
    for (int i = 0; i < 2; i++)
#pragma unroll
        for (int j = 0; j < 4; j++) accr[i][j] = (f32x4){0.f, 0.f, 0.f, 0.f};
#pragma unroll
    for (int ks = 0; ks < 2; ks++) {
        const int kofs = ks * 64 + lg * 16;
        bf16x8 bkr_[4];
#pragma unroll
        for (int jt = 0; jt < 4; jt++) {
            int j = w * 64 + jt * 16 + lq;
            int jr = j > 254 ? 254 : j;
            bkr_[jt] = *(const bf16x8*)(KRbase + (size_t)jr * 4608 + kofs);
        }
#pragma unroll
        for (int jt = 0; jt < 4; jt++) {
            accr[0][jt] = __builtin_amdgcn_mfma_f32_16x16x32_bf16(afq[ks][0], bkr_[jt], accr[0][jt], 0, 0, 0);
            accr[1][jt] = __builtin_amdgcn_mfma_f32_16x16x32_bf16(afq[ks][1], bkr_[jt], accr[1][jt], 0, 0, 0);
        }
    }

    // ---- issue S loads ----
    bf16x8 bk0_[8], bk1_[8];
#pragma unroll
    for (int jt = 0; jt < 8; jt++) {
        int key = w * 128 + jt * 16 + lq;
        bk0_[jt] = *(const bf16x8*)(Kbase + (size_t)key * 4608 + lg * 16);
        bk1_[jt] = *(const bf16x8*)(Kbase + (size_t)key * 4608 + 64 + lg * 16);
    }

    // ---- write Rq ----
#pragma unroll
    for (int it = 0; it < 2; it++)
#pragma unroll
        for (int jt = 0; jt < 4; jt++)
#pragma unroll
            for (int r = 0; r < 4; r++)
                RqPrel[(it * 16 + lg * 4 + r) * PR_LD + w * 64 + jt * 16 + lq] = f2bfu(accr[it][jt][r]);

    // ---- S MFMA ----
    f32x4 accs[2][8];
#pragma unroll
    for (int i = 0; i < 2; i++)
#pragma unroll
        for (int j = 0; j < 8; j++) accs[i][j] = (f32x4){0.f, 0.f, 0.f, 0.f};
#pragma unroll
    for (int jt = 0; jt < 8; jt++) {
        accs[0][jt] = __builtin_amdgcn_mfma_f32_16x16x32_bf16(afq[0][0], bk0_[jt], accs[0][jt], 0, 0, 0);
        accs[1][jt] = __builtin_amdgcn_mfma_f32_16x16x32_bf16(afq[0][1], bk0_[jt], accs[1][jt], 0, 0, 0);
    }
#pragma unroll
    for (int jt = 0; jt < 8; jt++) {
        accs[0][jt] = __builtin_amdgcn_mfma_f32_16x16x32_bf16(afq[1][0], bk1_[jt], accs[0][jt], 0, 0, 0);
        accs[1][jt] = __builtin_amdgcn_mfma_f32_16x16x32_bf16(afq[1][1], bk1_[jt], accs[1][jt], 0, 0, 0);
    }

    // ---- issue VR prefetch (hides under barrier + epilogue) ----
    const __hip_bfloat16* vTb  = vT  + (((size_t)(b * NH_ + h) * 64) + w * 16 + lq) * 512 + lg * 8;
    const __hip_bfloat16* vrTb = vrT + ((size_t)(h * 64) + w * 16 + lq) * 256 + lg * 8;
    bf16x8 vrpre[8];
#pragma unroll
    for (int ks = 0; ks < 8; ks++)
        vrpre[ks] = *(const bf16x8*)(vrTb + ks * 32);

    __syncthreads();

    // ---- issue V prefetch early: covered by S-epilogue + exp + prel VALU work ----
    bf16x8 bvpre[8];
#pragma unroll
    for (int ks = 0; ks < 8; ks++)
        bvpre[ks] = *(const bf16x8*)(vTb + ks * 32);

    // ---- S epilogue ----
#pragma unroll
    for (int it = 0; it < 2; it++) {
#pragma unroll
        for (int r = 0; r < 4; r++) {
            int q = it * 16 + lg * 4 + r;
            int qg = qt * 32 + q;
            float mx = -INFINITY;
#pragma unroll
            for (int jt = 0; jt < 8; jt++) {
                int k = w * 128 + jt * 16 + lq;
                int jc = k - qg + 127;
                jc = jc < 0 ? 0 : (jc > 254 ? 254 : jc);
                float s = (accs[it][jt][r] + bfu2f(RqPrel[q * PR_LD + jc])) * COEF_ + maskb[k];
                accs[it][jt][r] = s;
                mx = fmaxf(mx, s);
            }
#pragma unroll
            for (int off = 1; off < 16; off <<= 1) mx = fmaxf(mx, __shfl_xor(mx, off, 64));
            if (lq == 0) mstat[q * 4 + w] = mx;
        }
    }
    __syncthreads();

    // ---- exp + row sums + write P ----
#pragma unroll
    for (int it = 0; it < 2; it++) {
#pragma unroll
        for (int r = 0; r < 4; r++) {
            int q = it * 16 + lg * 4 + r;
            float4 mv = *(const float4*)&mstat[q * 4];
            float gm = fmaxf(fmaxf(mv.x, mv.y), fmaxf(mv.z, mv.w));
            float ssum = 0.f;
#pragma unroll
            for (int jt = 0; jt < 8; jt++) {
                int k = w * 128 + jt * 16 + lq;
                float p = __expf(accs[it][jt][r] - gm);
                ssum += p;
                Ps[q * PS_LD + k] = f2bfu(p);
            }
#pragma unroll
            for (int off = 1; off < 16; off <<= 1) ssum += __shfl_xor(ssum, off, 64);
            if (lq == 0) sstat[q * 4 + w] = ssum;
        }
    }
    __syncthreads();

    // ---- prel construction ----
    {
        int q = t >> 3, sub = t & 7;
        int qg = qt * 32 + q;
#pragma unroll
        for (int jj = 0; jj < 32; jj++) {
            int j = sub + 8 * jj;
            if (j == 0 || j == 254) continue;
            if (j == 255) { RqPrel[q * PR_LD + 255] = 0; continue; }
            int k = qg + j - 127;
            unsigned short val = ((unsigned)k < 512u) ? Ps[q * PS_LD + k] : (unsigned short)0;
            RqPrel[q * PR_LD + j] = val;
        }
    }
    {
        int task = t >> 2, ts = t & 3;
        int q = task >> 1, side = task & 1;
        int qg = qt * 32 + q;
        float sum = 0.f;
        if (side == 0) {
            int hi = qg - 127;
            for (int k = ts; k <= hi; k += 4) sum += bfu2f(Ps[q * PS_LD + k]);
        } else {
            for (int k = qg + 127 + ts; k < 512; k += 4) sum += bfu2f(Ps[q * PS_LD + k]);
        }
        sum += __shfl_xor(sum, 1, 64);
        sum += __shfl_xor(sum, 2, 64);
        if (ts == 0) RqPrel[q * PR_LD + (side == 0 ? 0 : 254)] = f2bfu(sum);
    }
    __syncthreads();

    // ---- PV phase ----
    f32x4 accv[2];
    accv[0] = (f32x4){0.f, 0.f, 0.f, 0.f};
    accv[1] = (f32x4){0.f, 0.f, 0.f, 0.f};

#pragma unroll
    for (int ks = 0; ks < 8; ks++) {
        bf16x8 pa0 = *(const bf16x8*)((const char*)Ps + (size_t)lq * (PS_LD * 2) + ks * 64 + lg * 16);
        bf16x8 pa1 = *(const bf16x8*)((const char*)Ps + (size_t)(16 + lq) * (PS_LD * 2) + ks * 64 + lg * 16);
        accv[0] = __builtin_amdgcn_mfma_f32_16x16x32_bf16(pa0, bvpre[ks], accv[0], 0, 0, 0);
        accv[1] = __builtin_amdgcn_mfma_f32_16x16x32_bf16(pa1, bvpre[ks], accv[1], 0, 0, 0);
    }
#pragma unroll
    for (int ks = 8; ks < 16; ks++) {
        bf16x8 bv = *(const bf16x8*)(vTb + ks * 32);
        bf16x8 pa0 = *(const bf16x8*)((const char*)Ps + (size_t)lq * (PS_LD * 2) + ks * 64 + lg * 16);
        bf16x8 pa1 = *(const bf16x8*)((const char*)Ps + (size_t)(16 + lq) * (PS_LD * 2) + ks * 64 + lg * 16);
        accv[0] = __builtin_amdgcn_mfma_f32_16x16x32_bf16(pa0, bv, accv[0], 0, 0, 0);
        accv[1] = __builtin_amdgcn_mfma_f32_16x16x32_bf16(pa1, bv, accv[1], 0, 0, 0);
    }
#pragma unroll
    for (int ks = 0; ks < 8; ks++) {
        bf16x8 pa0 = *(const bf16x8*)((const char*)RqPrel + (size_t)lq * (PR_LD * 2) + ks * 64 + lg * 16);
        bf16x8 pa1 = *(const bf16x8*)((const char*)RqPrel + (size_t)(16 + lq) * (PR_LD * 2) + ks * 64 + lg * 16);
        accv[0] = __builtin_amdgcn_mfma_f32_16x16x32_bf16(pa0, vrpre[ks], accv[0], 0, 0, 0);
        accv[1] = __builtin_amdgcn_mfma_f32_16x16x32_bf16(pa1, vrpre[ks], accv[1], 0, 0, 0);
    }

#pragma unroll
    for (int it = 0; it < 2; it++) {
#pragma unroll
        for (int r = 0; r < 4; r++) {
            int q = it * 16 + lg * 4 + r;
            float4 sv = *(const float4*)&sstat[q * 4];
            float inv = 1.f / (sv.x + sv.y + sv.z + sv.w);
            ctxb[(size_t)(b * L_ + qt * 32 + q) * 768 + h * 64 + w * 16 + lq] =
                __float2bfloat16(accv[it][r] * inv);
        }
    }
}

// ---------------- host ----------------

extern "C" void kernel_launch(void* const* d_in, const int* in_sizes, int n_in,
                              void* d_out, int out_size, void* d_ws, size_t ws_size,
                              hipStream_t stream)
{
    const int*   tok    = (const int*)d_in[0];
    const int*   seg    = (const int*)d_in[1];
    const int*   maskp  = (const int*)d_in[2];
    const float* temb   = (const float*)d_in[3];
    const float* semb   = (const float*)d_in[4];
    const float* esc    = (const float*)d_in[5];
    const float* ebi    = (const float*)d_in[6];
    const float* Wq     = (const float*)d_in[7];
    const float* bq     = (const float*)d_in[8];
    const float* Wk     = (const float*)d_in[9];
    const float* bk     = (const float*)d_in[10];
    const float* Wv     = (const float*)d_in[11];
    const float* bv     = (const float*)d_in[12];
    const float* relpos = (const float*)d_in[13];
    const float* Wo     = (const float*)d_in[14];
    const float* bo     = (const float*)d_in[15];
    const float* ln1s   = (const float*)d_in[16];
    const float* ln1b   = (const float*)d_in[17];
    const float* W1     = (const float*)d_in[18];
    const float* b1     = (const float*)d_in[19];
    const float* W2     = (const float*)d_in[20];
    const float* b2     = (const float*)d_in[21];
    const float* ln2s   = (const float*)d_in[22];
    const float* ln2b   = (const float*)d_in[23];

    const size_t NX = (size_t)ROWS * H_;
    float* x       = (float*)d_ws;
    float* x2      = x + NX;
    float* y       = x2 + NX;
    float* qkvbias = y + NX;                                   // 2304 f32
    __hip_bfloat16* xb    = (__hip_bfloat16*)(qkvbias + 2304); // [ROWS][768]
    __hip_bfloat16* x2b   = xb    + NX;
    __hip_bfloat16* ctxb  = x2b   + NX;
    __hip_bfloat16* qkvb  = ctxb  + NX;                        // [MEXT][2304]
    __hip_bfloat16* vT    = qkvb  + (size_t)MEXT * 2304;       // 4*12*64*512
    __hip_bfloat16* vrT   = vT    + (size_t)B_ * NH_ * 64 * 512; // 12*64*256
    __hip_bfloat16* relb  = vrT   + (size_t)NH_ * 64 * 256;    // 255*768
    __hip_bfloat16* WtQ   = relb  + (size_t)NR_ * H_;          // 2304*768
    __hip_bfloat16* WtO   = WtQ   + (size_t)2304 * H_;         // 768*768
    __hip_bfloat16* WtW1  = WtO   + (size_t)H_ * H_;           // 3072*768
    __hip_bfloat16* WtW2  = WtW1  + (size_t)M_ * H_;           // 768*3072
    __hip_bfloat16* h1b   = WtW2  + (size_t)H_ * M_;           // 2048*3072

    float* spill = (float*)qkvb;   // split-K partials alias qkvb/vT (dead after attn)

    dim3 blk(256);
    dim3 blk512(512);

    embed_ln_kernel<<<ROWS, blk, 0, stream>>>(tok, seg, temb, semb, esc, ebi, x, xb);

    for (int l = 0; l < NL_; l++) {
        const float* wq = Wq + (size_t)l * H_ * H_;
        const float* wk = Wk + (size_t)l * H_ * H_;
        const float* wv = Wv + (size_t)l * H_ * H_;
        const float* wo = Wo + (size_t)l * H_ * H_;
        const float* w1 = W1 + (size_t)l * H_ * M_;
        const float* w2 = W2 + (size_t)l * M_ * H_;

        pack_layer_kernel<<<dim3(96, 24, 7), blk, 0, stream>>>(
            wq, wk, wv, wo, w1, w2,
            bq + (size_t)l * H_, bk + (size_t)l * H_, bv + (size_t)l * H_,
            relpos + (size_t)l * NR_ * H_,
            WtQ, WtO, WtW1, WtW2, qkvbias, relb);

        // merged QKV + rel projection: rows<2048 from xb, rows>=2048 from relb (A2)
        gemm_bf16_kernel<<<dim3(36, 18), blk512, 0, stream>>>(xb, relb, WtQ, qkvbias,
                                                              nullptr, qkvb, nullptr, 0,
                                                              MEXT, 2304, H_, 0, H_);
        transpose_vvr_kernel<<<dim3(36, 12), blk, 0, stream>>>(qkvb, vT, vrT);

        attn_kernel<<<dim3(768), blk, 0, stream>>>(qkvb, vT, vrT, maskp, ctxb);

        // O projection: split-K x2 (768 -> 2x384); bias added in add_ln
        gemm_bf16_kernel<<<dim3(12, 16, 2), blk512, 0, stream>>>(ctxb, nullptr, WtO, nullptr,
                                                                 y, nullptr, spill, NX,
                                                                 ROWS, H_, H_, 0, 384);
        add_ln_kernel<<<ROWS, blk, 0, stream>>>(x, y, spill, nullptr, bo + (size_t)l * H_,
                                                ln1s + (size_t)l * H_, ln1b + (size_t)l * H_, x2, x2b);

        // MLP
        gemm_bf16_kernel<<<dim3(48, 16), blk512, 0, stream>>>(x2b, nullptr, WtW1, b1 + (size_t)l * M_,
                                                              nullptr, h1b, nullptr, 0,
                                                              ROWS, M_, H_, 1, H_);
        gemm_bf16_kernel<<<dim3(12, 16, 3), blk512, 0, stream>>>(h1b, nullptr, WtW2, nullptr,
                                                                 y, nullptr, spill, NX,
                                                                 ROWS, H_, M_, 0, 1024);

        float* outp = (l == NL_ - 1) ? (float*)d_out : x;
        __hip_bfloat16* outbp = (l == NL_ - 1) ? nullptr : xb;
        add_ln_kernel<<<ROWS, blk, 0, stream>>>(x2, y, spill, spill + NX, b2 + (size_t)l * H_,
                                                ln2s + (size_t)l * H_, ln2b + (size_t)l * H_, outp, outbp);
    }
}

// Round 16
// 733.309 us; speedup vs baseline: 1.0595x; 1.0595x over previous
//
#include <hip/hip_runtime.h>
#include <hip/hip_bf16.h>
#include <math.h>

#define B_   4
#define L_   512
#define H_   768
#define NH_  12
#define HD_  64
#define M_   3072
#define NL_  6
#define RD_  128
#define NR_  255          // 2*RD-1
#define ROWS (B_*L_)      // 2048
#define MEXT 2304         // ROWS + NR_ + 1 pad (merged QKV+rel A rows)
#define COEF_ 0.125f      // 1/sqrt(64)

typedef __attribute__((ext_vector_type(8))) short bf16x8;
typedef __attribute__((ext_vector_type(4))) float f32x4;

// ---------------- utility ----------------

static __device__ __forceinline__ float wave_reduce_sum(float v) {
#pragma unroll
    for (int off = 32; off > 0; off >>= 1) v += __shfl_xor(v, off, 64);
    return v;
}

static __device__ __forceinline__ float gelu_f(float x) {
    float x3 = x * x * x;
    return 0.5f * x * (1.f + tanhf(0.7978845608028654f * (x + 0.044715f * x3)));
}

static __device__ __forceinline__ unsigned short f2bfu(float v) {
    __hip_bfloat16 h = __float2bfloat16(v);
    return *(unsigned short*)&h;
}

static __device__ __forceinline__ float bfu2f(unsigned short u) {
    union { float f; unsigned int i; } x;
    x.i = ((unsigned int)u) << 16;
    return x.f;
}

// async global->LDS, 16B per lane; LDS dest = wave-uniform base + lane*16
static __device__ __forceinline__ void gload16(const void* g, void* l) {
    __builtin_amdgcn_global_load_lds(
        (const __attribute__((address_space(1))) void*)g,
        (__attribute__((address_space(3))) void*)l,
        16, 0, 0);
}

// ---------------- embedding + LN (fp32 out + bf16 twin) ----------------

__global__ __launch_bounds__(256) void embed_ln_kernel(
    const int* __restrict__ tok, const int* __restrict__ seg,
    const float* __restrict__ temb, const float* __restrict__ semb,
    const float* __restrict__ sc, const float* __restrict__ bi,
    float* __restrict__ out, __hip_bfloat16* __restrict__ outb)
{
    int row = blockIdx.x;
    int t = threadIdx.x;
    int tid = tok[row], sid = seg[row];
    const float* tp = temb + (size_t)tid * H_;
    const float* sp = semb + (size_t)sid * H_;
    float v[3];
#pragma unroll
    for (int j = 0; j < 3; j++) { int idx = t + j * 256; v[j] = tp[idx] + sp[idx]; }

    __shared__ float red[4];
    __shared__ float bc;
    int lane = t & 63, wid = t >> 6;

    float s = v[0] + v[1] + v[2];
    s = wave_reduce_sum(s);
    if (lane == 0) red[wid] = s;
    __syncthreads();
    if (t == 0) bc = (red[0] + red[1] + red[2] + red[3]) * (1.f / H_);
    __syncthreads();
    float mean = bc;

    float c[3]; float ss = 0.f;
#pragma unroll
    for (int j = 0; j < 3; j++) { c[j] = v[j] - mean; ss += c[j] * c[j]; }
    ss = wave_reduce_sum(ss);
    __syncthreads();
    if (lane == 0) red[wid] = ss;
    __syncthreads();
    if (t == 0) bc = rsqrtf((red[0] + red[1] + red[2] + red[3]) * (1.f / H_) + 1e-12f);
    __syncthreads();
    float r = bc;
#pragma unroll
    for (int j = 0; j < 3; j++) {
        int idx = t + j * 256;
        float o = c[j] * r * sc[idx] + bi[idx];
        out[(size_t)row * H_ + idx] = o;
        outb[(size_t)row * H_ + idx] = __float2bfloat16(o);
    }
}

// ---------------- residual add (+partials +bias) + LN (fp32 out + optional bf16 twin) ----------------

__global__ __launch_bounds__(256) void add_ln_kernel(
    const float* __restrict__ x, const float* __restrict__ p0,
    const float* __restrict__ p1, const float* __restrict__ p2,
    const float* __restrict__ bias,
    const float* __restrict__ sc, const float* __restrict__ bi,
    float* __restrict__ out, __hip_bfloat16* __restrict__ outb)
{
    int row = blockIdx.x;
    int t = threadIdx.x;
    const float* xp = x + (size_t)row * H_;
    const float* q0 = p0 + (size_t)row * H_;
    const float* q1 = p1 ? p1 + (size_t)row * H_ : nullptr;
    const float* q2 = p2 ? p2 + (size_t)row * H_ : nullptr;
    float v[3];
#pragma unroll
    for (int j = 0; j < 3; j++) {
        int idx = t + j * 256;
        float a = xp[idx] + q0[idx];
        if (q1) a += q1[idx];
        if (q2) a += q2[idx];
        if (bias) a += bias[idx];
        v[j] = a;
    }

    __shared__ float red[4];
    __shared__ float bc;
    int lane = t & 63, wid = t >> 6;

    float s = v[0] + v[1] + v[2];
    s = wave_reduce_sum(s);
    if (lane == 0) red[wid] = s;
    __syncthreads();
    if (t == 0) bc = (red[0] + red[1] + red[2] + red[3]) * (1.f / H_);
    __syncthreads();
    float mean = bc;

    float c[3]; float ss = 0.f;
#pragma unroll
    for (int j = 0; j < 3; j++) { c[j] = v[j] - mean; ss += c[j] * c[j]; }
    ss = wave_reduce_sum(ss);
    __syncthreads();
    if (lane == 0) red[wid] = ss;
    __syncthreads();
    if (t == 0) bc = rsqrtf((red[0] + red[1] + red[2] + red[3]) * (1.f / H_) + 1e-12f);
    __syncthreads();
    float r = bc;
#pragma unroll
    for (int j = 0; j < 3; j++) {
        int idx = t + j * 256;
        float o = c[j] * r * sc[idx] + bi[idx];
        out[(size_t)row * H_ + idx] = o;
        if (outb) outb[(size_t)row * H_ + idx] = __float2bfloat16(o);
    }
}

// ---------------- consolidated per-layer weight/bias/rel pack ----------------

__global__ __launch_bounds__(256) void pack_layer_kernel(
    const float* __restrict__ wq, const float* __restrict__ wk, const float* __restrict__ wv,
    const float* __restrict__ wo, const float* __restrict__ w1, const float* __restrict__ w2,
    const float* __restrict__ bqL, const float* __restrict__ bkL, const float* __restrict__ bvL,
    const float* __restrict__ relL,
    __hip_bfloat16* __restrict__ WtQ, __hip_bfloat16* __restrict__ WtO,
    __hip_bfloat16* __restrict__ WtW1, __hip_bfloat16* __restrict__ WtW2,
    float* __restrict__ qkvbias, __hip_bfloat16* __restrict__ relb)
{
    const int z = blockIdx.z;
    const int t = threadIdx.x;
    if (z == 6) {
        int id = blockIdx.y * 96 + blockIdx.x;
        if (id < 765) {
            int i = id * 256 + t;              // 765*256 = 195840 = 255*768 exactly
            relb[i] = __float2bfloat16(relL[i]);
        } else if (id < 774) {
            int i = (id - 765) * 256 + t;
            if (i < 2304)
                qkvbias[i] = i < 768 ? bqL[i] : (i < 1536 ? bkL[i - 768] : bvL[i - 1536]);
        }
        return;
    }
    const float* in; __hip_bfloat16* out; int K, N;
    int bx = blockIdx.x, by = blockIdx.y;
    if (z < 4) {
        if (bx >= 24) return;
        K = 768; N = 768;
        in = (z == 0) ? wq : (z == 1) ? wk : (z == 2) ? wv : wo;
        out = (z < 3) ? WtQ + (size_t)z * H_ * H_ : WtO;
    } else if (z == 4) {
        K = 768; N = 3072; in = w1; out = WtW1;
    } else {
        K = 3072; N = 768; in = w2; out = WtW2;
        int tmp = bx; bx = by; by = tmp;       // bx<24 (N), by<96 (K)
    }
    __shared__ float tile[32][33];
    int bX = bx * 32, bY = by * 32;
    int tx = t & 31, ty = t >> 5;
#pragma unroll
    for (int i = 0; i < 4; i++)
        tile[ty + 8 * i][tx] = in[(size_t)(bY + ty + 8 * i) * N + bX + tx];
    __syncthreads();
#pragma unroll
    for (int i = 0; i < 4; i++)
        out[(size_t)(bX + ty + 8 * i) * K + bY + tx] = __float2bfloat16(tile[tx][ty + 8 * i]);
}

// ---------------- fused V / VR transpose ----------------
// bx<32: qkvb[MEXT][2304] rows 0..2047 cols 1536.. -> vT[b][h][64][512]
// bx>=32: qkvb rows 2048+j cols 1536..              -> vrT[h][64][256] (j>=255 -> 0)

__global__ __launch_bounds__(256) void transpose_vvr_kernel(
    const __hip_bfloat16* __restrict__ qkvb,
    __hip_bfloat16* __restrict__ vT, __hip_bfloat16* __restrict__ vrT)
{
    __shared__ unsigned short tile[64][72];
    const int bx = blockIdx.x;
    const int h  = blockIdx.y;
    const int t = threadIdx.x;
    const int r = t >> 2, c0 = (t & 3) * 16;
    if (bx < 32) {
        const int kb = bx * 64;
        const unsigned short* src = (const unsigned short*)qkvb + (size_t)(kb + r) * 2304 + 1536 + h * 64 + c0;
        *(uint4*)&tile[r][c0]     = *(const uint4*)src;
        *(uint4*)&tile[r][c0 + 8] = *(const uint4*)(src + 8);
        __syncthreads();
        unsigned short outv[16];
#pragma unroll
        for (int i = 0; i < 16; i++) outv[i] = tile[c0 + i][r];
        unsigned short* dst = (unsigned short*)vT +
            ((size_t)((kb >> 9) * NH_ + h) * 64 + r) * 512 + (kb & 511) + c0;
        *(uint4*)dst       = *(uint4*)&outv[0];
        *(uint4*)(dst + 8) = *(uint4*)&outv[8];
    } else {
        const int jb = (bx - 32) * 64;
        const int j = jb + r;
        if (j < NR_) {
            const unsigned short* src = (const unsigned short*)qkvb + (size_t)(2048 + j) * 2304 + 1536 + h * 64 + c0;
            *(uint4*)&tile[r][c0]     = *(const uint4*)src;
            *(uint4*)&tile[r][c0 + 8] = *(const uint4*)(src + 8);
        } else {
#pragma unroll
            for (int i = 0; i < 16; i++) tile[r][c0 + i] = 0;
        }
        __syncthreads();
        unsigned short outv[16];
#pragma unroll
        for (int i = 0; i < 16; i++) outv[i] = tile[c0 + i][r];
        unsigned short* dst = (unsigned short*)vrT + ((size_t)(h * 64) + r) * 256 + jb + c0;
        *(uint4*)dst       = *(uint4*)&outv[0];
        *(uint4*)(dst + 8) = *(uint4*)&outv[8];
    }
}

// ---------------- bf16 MFMA GEMM: 128x64 tile, 8 waves, 3 blocks/CU (24 waves/CU) ----------------

#define TK 64

__global__ __launch_bounds__(512, 6) void gemm_bf16_kernel(
    const __hip_bfloat16* __restrict__ A, const __hip_bfloat16* __restrict__ Bt,
    const float* __restrict__ bias, float* __restrict__ Cf, __hip_bfloat16* __restrict__ Cb,
    float* __restrict__ CfX, size_t xstride,
    int M, int N, int K, int act, int ksplit)
{
    __shared__ __hip_bfloat16 As[2][128 * TK];
    __shared__ __hip_bfloat16 Bs[2][64 * TK];
    const int t = threadIdx.x;
    const int lane = t & 63;
    const int wid = t >> 6;                 // 0..7
    const int lq = lane & 15, lg = lane >> 4;
    const int wm = (wid & 3) * 32, wn = (wid >> 2) * 32;

    const int nbx = gridDim.x;
    const int nwg = nbx * gridDim.y;
    int wgid = blockIdx.y * nbx + blockIdx.x;
    if ((nwg & 7) == 0) { int qq = nwg >> 3; wgid = (wgid & 7) * qq + (wgid >> 3); }
    const int bm = (wgid / nbx) * 128, bn = (wgid % nbx) * 64;
    const int kbase = blockIdx.z * ksplit;

    f32x4 acc[2][2];
#pragma unroll
    for (int i = 0; i < 2; i++)
#pragma unroll
        for (int j = 0; j < 2; j++) acc[i][j] = (f32x4){0.f, 0.f, 0.f, 0.f};

    const int rl = t >> 3;                              // 0..63
    const int cswz = (((t & 7) * 16) ^ ((rl & 7) << 4)) >> 1;   // elements
    const __hip_bfloat16* ga[2];
    const __hip_bfloat16* gb;
    int lofsA[2], lofsB;
#pragma unroll
    for (int c = 0; c < 2; c++) {
        int rowa = bm + c * 64 + rl; if (rowa >= M) rowa = M - 1;
        ga[c] = A + (size_t)rowa * K + kbase + cswz;
        lofsA[c] = (c * 64 + wid * 8) * TK;
    }
    gb = Bt + (size_t)(bn + rl) * K + kbase + cswz;
    lofsB = (wid * 8) * TK;

    const int nt = ksplit / TK;
    gload16(ga[0], &As[0][lofsA[0]]);
    gload16(ga[1], &As[0][lofsA[1]]);
    gload16(gb,    &Bs[0][lofsB]);
    __syncthreads();

    int cur = 0;
    for (int kt = 0; kt < nt; kt++) {
        if (kt + 1 < nt) {
            const int koff = (kt + 1) * TK;
            gload16(ga[0] + koff, &As[cur ^ 1][lofsA[0]]);
            gload16(ga[1] + koff, &As[cur ^ 1][lofsA[1]]);
            gload16(gb + koff,    &Bs[cur ^ 1][lofsB]);
        }
#pragma unroll
        for (int kh = 0; kh < 2; kh++) {
            const int kb = kh * 64 + lg * 16;
            bf16x8 af[2], bfr[2];
#pragma unroll
            for (int i = 0; i < 2; i++) {
                int ra = wm + i * 16 + lq;
                af[i] = *(const bf16x8*)((const char*)&As[cur][0] + ra * 128 + (kb ^ ((ra & 7) << 4)));
            }
#pragma unroll
            for (int j = 0; j < 2; j++) {
                int rb = wn + j * 16 + lq;
                bfr[j] = *(const bf16x8*)((const char*)&Bs[cur][0] + rb * 128 + (kb ^ ((rb & 7) << 4)));
            }
#pragma unroll
            for (int i = 0; i < 2; i++)
#pragma unroll
                for (int j = 0; j < 2; j++)
                    acc[i][j] = __builtin_amdgcn_mfma_f32_16x16x32_bf16(af[i], bfr[j], acc[i][j], 0, 0, 0);
        }
        __syncthreads();
        cur ^= 1;
    }

    float* outf = (blockIdx.z == 0) ? Cf : (CfX + (size_t)(blockIdx.z - 1) * xstride);
#pragma unroll
    for (int i = 0; i < 2; i++) {
#pragma unroll
        for (int j = 0; j < 2; j++) {
            int col = bn + wn + j * 16 + lq;
            float bsv = bias ? bias[col] : 0.f;
            int row0 = bm + wm + i * 16 + lg * 4;
#pragma unroll
            for (int rr = 0; rr < 4; rr++) {
                int row = row0 + rr;
                if (row >= M) continue;
                float v = acc[i][j][rr] + bsv;
                if (act) v = gelu_f(v);
                if (Cb && blockIdx.z == 0) Cb[(size_t)row * N + col] = __float2bfloat16(v);
                else                       outf[(size_t)row * N + col] = v;
            }
        }
    }
}

// ---------------- MFMA rel-pos attention ----------------
// 1D grid of 768, XCD-aware decode. 256 threads (4 waves). 32 q-rows per block.
// qkvb [MEXT][2304]: rows 0..2047 = Q|K|V of tokens; rows 2048..2302 = *|KR|VR of rel emb.

#define PS_LD 520   // bf16 elems per Ps row (512 + 8 pad)
#define PR_LD 264   // bf16 elems per Rq/prel row (256 + 8 pad)

__global__ __launch_bounds__(256, 3) void attn_kernel(
    const __hip_bfloat16* __restrict__ qkvb,  // [MEXT][2304]
    const __hip_bfloat16* __restrict__ vT,    // [B][NH][64][512]
    const __hip_bfloat16* __restrict__ vrT,   // [NH][64][256] (col 255 zero)
    const int* __restrict__ mask,
    __hip_bfloat16* __restrict__ ctxb)        // [2048][768]
{
    __shared__ unsigned short RqPrel[32 * PR_LD];
    __shared__ unsigned short Ps[32 * PS_LD];
    __shared__ float mstat[32 * 4];
    __shared__ float sstat[32 * 4];
    __shared__ float maskb[512];

    const int i_ = blockIdx.x;
    const int c_ = i_ & 7, s_ = i_ >> 3;
    const int p_ = c_ + 8 * (s_ >> 4);
    const int qt = s_ & 15;
    const int b = p_ / 12, h = p_ % 12;

    const int t = threadIdx.x;
    const int lane = t & 63, w = t >> 6;
    const int lq = lane & 15, lg = lane >> 4;

    maskb[t]       = mask[b * L_ + t]       ? 0.f : -1e30f;
    maskb[t + 256] = mask[b * L_ + t + 256] ? 0.f : -1e30f;

    const char* Qbase  = (const char*)qkvb + ((size_t)(b * L_ + qt * 32) * 2304 + h * 64) * 2;
    const char* Kbase  = (const char*)qkvb + ((size_t)(b * L_) * 2304 + 768 + h * 64) * 2;
    const char* KRbase = (const char*)qkvb + ((size_t)2048 * 2304 + 768 + h * 64) * 2;

    // hoist Q fragments once (reused by R and S phases)
    bf16x8 afq[2][2];
#pragma unroll
    for (int ks = 0; ks < 2; ks++) {
        const int kofs = ks * 64 + lg * 16;
        afq[ks][0] = *(const bf16x8*)(Qbase + (size_t)lq * 4608 + kofs);
        afq[ks][1] = *(const bf16x8*)(Qbase + (size_t)(16 + lq) * 4608 + kofs);
    }

    // ---- R phase: Rq[32][256] = Q @ KR^T ----
    {
        f32x4 accr[2][4];
#pragma unroll
        for (int i = 0; i < 2; i++)
#pragma unroll
            for (int j = 0; j < 4; j++) accr[i][j] = (f32x4){0.f, 0.f, 0.f, 0.f};
#pragma unroll
        for (int ks = 0; ks < 2; ks++) {
            const int kofs = ks * 64 + lg * 16;
            bf16x8 bkr_[4];
#pragma unroll
            for (int jt = 0; jt < 4; jt++) {
                int j = w * 64 + jt * 16 + lq;
                int jr = j > 254 ? 254 : j;
                bkr_[jt] = *(const bf16x8*)(KRbase + (size_t)jr * 4608 + kofs);
            }
#pragma unroll
            for (int jt = 0; jt < 4; jt++) {
                accr[0][jt] = __builtin_amdgcn_mfma_f32_16x16x32_bf16(afq[ks][0], bkr_[jt], accr[0][jt], 0, 0, 0);
                accr[1][jt] = __builtin_amdgcn_mfma_f32_16x16x32_bf16(afq[ks][1], bkr_[jt], accr[1][jt], 0, 0, 0);
            }
        }
#pragma unroll
        for (int it = 0; it < 2; it++)
#pragma unroll
            for (int jt = 0; jt < 4; jt++)
#pragma unroll
                for (int r = 0; r < 4; r++)
                    RqPrel[(it * 16 + lg * 4 + r) * PR_LD + w * 64 + jt * 16 + lq] = f2bfu(accr[it][jt][r]);
    }
    __syncthreads();

    // ---- S phase: Q @ K^T (wave w owns key strip w*128..+128), batched loads ----
    f32x4 accs[2][8];
#pragma unroll
    for (int i = 0; i < 2; i++)
#pragma unroll
        for (int j = 0; j < 8; j++) accs[i][j] = (f32x4){0.f, 0.f, 0.f, 0.f};
#pragma unroll
    for (int ks = 0; ks < 2; ks++) {
        const int kofs = ks * 64 + lg * 16;
        bf16x8 bk_[8];
#pragma unroll
        for (int jt = 0; jt < 8; jt++) {
            int key = w * 128 + jt * 16 + lq;
            bk_[jt] = *(const bf16x8*)(Kbase + (size_t)key * 4608 + kofs);
        }
#pragma unroll
        for (int jt = 0; jt < 8; jt++) {
            accs[0][jt] = __builtin_amdgcn_mfma_f32_16x16x32_bf16(afq[ks][0], bk_[jt], accs[0][jt], 0, 0, 0);
            accs[1][jt] = __builtin_amdgcn_mfma_f32_16x16x32_bf16(afq[ks][1], bk_[jt], accs[1][jt], 0, 0, 0);
        }
    }

    // ---- S epilogue: add rel score + mask ----
#pragma unroll
    for (int it = 0; it < 2; it++) {
#pragma unroll
        for (int r = 0; r < 4; r++) {
            int q = it * 16 + lg * 4 + r;
            int qg = qt * 32 + q;
            float mx = -INFINITY;
#pragma unroll
            for (int jt = 0; jt < 8; jt++) {
                int k = w * 128 + jt * 16 + lq;
                int jc = k - qg + 127;
                jc = jc < 0 ? 0 : (jc > 254 ? 254 : jc);
                float s = (accs[it][jt][r] + bfu2f(RqPrel[q * PR_LD + jc])) * COEF_ + maskb[k];
                accs[it][jt][r] = s;
                mx = fmaxf(mx, s);
            }
#pragma unroll
            for (int off = 1; off < 16; off <<= 1) mx = fmaxf(mx, __shfl_xor(mx, off, 64));
            if (lq == 0) mstat[q * 4 + w] = mx;
        }
    }
    __syncthreads();

    // ---- exp + row sums + write P ----
#pragma unroll
    for (int it = 0; it < 2; it++) {
#pragma unroll
        for (int r = 0; r < 4; r++) {
            int q = it * 16 + lg * 4 + r;
            float4 mv = *(const float4*)&mstat[q * 4];
            float gm = fmaxf(fmaxf(mv.x, mv.y), fmaxf(mv.z, mv.w));
            float ssum = 0.f;
#pragma unroll
            for (int jt = 0; jt < 8; jt++) {
                int k = w * 128 + jt * 16 + lq;
                float p = __expf(accs[it][jt][r] - gm);
                ssum += p;
                Ps[q * PS_LD + k] = f2bfu(p);
            }
#pragma unroll
            for (int off = 1; off < 16; off <<= 1) ssum += __shfl_xor(ssum, off, 64);
            if (lq == 0) sstat[q * 4 + w] = ssum;
        }
    }
    __syncthreads();

    // ---- prel construction + PV operand prefetch ----
    const __hip_bfloat16* vTb  = vT  + (((size_t)(b * NH_ + h) * 64) + w * 16 + lq) * 512 + lg * 8;
    const __hip_bfloat16* vrTb = vrT + ((size_t)(h * 64) + w * 16 + lq) * 256 + lg * 8;
    bf16x8 bvpre[8], vrpre[8];
#pragma unroll
    for (int ks = 0; ks < 8; ks++) {
        bvpre[ks] = *(const bf16x8*)(vTb + ks * 32);
        vrpre[ks] = *(const bf16x8*)(vrTb + ks * 32);
    }
    {
        int q = t >> 3, sub = t & 7;
        int qg = qt * 32 + q;
#pragma unroll
        for (int jj = 0; jj < 32; jj++) {
            int j = sub + 8 * jj;
            if (j == 0 || j == 254) continue;
            if (j == 255) { RqPrel[q * PR_LD + 255] = 0; continue; }
            int k = qg + j - 127;
            unsigned short val = ((unsigned)k < 512u) ? Ps[q * PS_LD + k] : (unsigned short)0;
            RqPrel[q * PR_LD + j] = val;
        }
    }
    {
        int task = t >> 2, ts = t & 3;
        int q = task >> 1, side = task & 1;
        int qg = qt * 32 + q;
        float sum = 0.f;
        if (side == 0) {
            int hi = qg - 127;
            for (int k = ts; k <= hi; k += 4) sum += bfu2f(Ps[q * PS_LD + k]);
        } else {
            for (int k = qg + 127 + ts; k < 512; k += 4) sum += bfu2f(Ps[q * PS_LD + k]);
        }
        sum += __shfl_xor(sum, 1, 64);
        sum += __shfl_xor(sum, 2, 64);
        if (ts == 0) RqPrel[q * PR_LD + (side == 0 ? 0 : 254)] = f2bfu(sum);
    }
    __syncthreads();

    // ---- PV phase: out strip d in [w*16, w*16+16) ----
    f32x4 accv[2];
    accv[0] = (f32x4){0.f, 0.f, 0.f, 0.f};
    accv[1] = (f32x4){0.f, 0.f, 0.f, 0.f};

#pragma unroll
    for (int ks = 0; ks < 8; ks++) {
        bf16x8 pa0 = *(const bf16x8*)((const char*)Ps + (size_t)lq * (PS_LD * 2) + ks * 64 + lg * 16);
        bf16x8 pa1 = *(const bf16x8*)((const char*)Ps + (size_t)(16 + lq) * (PS_LD * 2) + ks * 64 + lg * 16);
        accv[0] = __builtin_amdgcn_mfma_f32_16x16x32_bf16(pa0, bvpre[ks], accv[0], 0, 0, 0);
        accv[1] = __builtin_amdgcn_mfma_f32_16x16x32_bf16(pa1, bvpre[ks], accv[1], 0, 0, 0);
    }
#pragma unroll
    for (int ks = 8; ks < 16; ks++) {
        bf16x8 bv = *(const bf16x8*)(vTb + ks * 32);
        bf16x8 pa0 = *(const bf16x8*)((const char*)Ps + (size_t)lq * (PS_LD * 2) + ks * 64 + lg * 16);
        bf16x8 pa1 = *(const bf16x8*)((const char*)Ps + (size_t)(16 + lq) * (PS_LD * 2) + ks * 64 + lg * 16);
        accv[0] = __builtin_amdgcn_mfma_f32_16x16x32_bf16(pa0, bv, accv[0], 0, 0, 0);
        accv[1] = __builtin_amdgcn_mfma_f32_16x16x32_bf16(pa1, bv, accv[1], 0, 0, 0);
    }
#pragma unroll
    for (int ks = 0; ks < 8; ks++) {
        bf16x8 pa0 = *(const bf16x8*)((const char*)RqPrel + (size_t)lq * (PR_LD * 2) + ks * 64 + lg * 16);
        bf16x8 pa1 = *(const bf16x8*)((const char*)RqPrel + (size_t)(16 + lq) * (PR_LD * 2) + ks * 64 + lg * 16);
        accv[0] = __builtin_amdgcn_mfma_f32_16x16x32_bf16(pa0, vrpre[ks], accv[0], 0, 0, 0);
        accv[1] = __builtin_amdgcn_mfma_f32_16x16x32_bf16(pa1, vrpre[ks], accv[1], 0, 0, 0);
    }

#pragma unroll
    for (int it = 0; it < 2; it++) {
#pragma unroll
        for (int r = 0; r < 4; r++) {
            int q = it * 16 + lg * 4 + r;
            float4 sv = *(const float4*)&sstat[q * 4];
            float inv = 1.f / (sv.x + sv.y + sv.z + sv.w);
            ctxb[(size_t)(b * L_ + qt * 32 + q) * 768 + h * 64 + w * 16 + lq] =
                __float2bfloat16(accv[it][r] * inv);
        }
    }
}

// ---------------- host ----------------

extern "C" void kernel_launch(void* const* d_in, const int* in_sizes, int n_in,
                              void* d_out, int out_size, void* d_ws, size_t ws_size,
                              hipStream_t stream)
{
    const int*   tok    = (const int*)d_in[0];
    const int*   seg    = (const int*)d_in[1];
    const int*   maskp  = (const int*)d_in[2];
    const float* temb   = (const float*)d_in[3];
    const float* semb   = (const float*)d_in[4];
    const float* esc    = (const float*)d_in[5];
    const float* ebi    = (const float*)d_in[6];
    const float* Wq     = (const float*)d_in[7];
    const float* bq     = (const float*)d_in[8];
    const float* Wk     = (const float*)d_in[9];
    const float* bk     = (const float*)d_in[10];
    const float* Wv     = (const float*)d_in[11];
    const float* bv     = (const float*)d_in[12];
    const float* relpos = (const float*)d_in[13];
    const float* Wo     = (const float*)d_in[14];
    const float* bo     = (const float*)d_in[15];
    const float* ln1s   = (const float*)d_in[16];
    const float* ln1b   = (const float*)d_in[17];
    const float* W1     = (const float*)d_in[18];
    const float* b1     = (const float*)d_in[19];
    const float* W2     = (const float*)d_in[20];
    const float* b2     = (const float*)d_in[21];
    const float* ln2s   = (const float*)d_in[22];
    const float* ln2b   = (const float*)d_in[23];

    const size_t NX = (size_t)ROWS * H_;
    float* x       = (float*)d_ws;
    float* x2      = x + NX;
    float* y       = x2 + NX;
    float* qkvbias = y + NX;                                   // 2304 f32
    __hip_bfloat16* xb    = (__hip_bfloat16*)(qkvbias + 2304); // [MEXT][768] (rows 2048.. = rel emb)
    __hip_bfloat16* x2b   = xb    + (size_t)MEXT * H_;
    __hip_bfloat16* ctxb  = x2b   + NX;
    __hip_bfloat16* qkvb  = ctxb  + NX;                        // [MEXT][2304]
    __hip_bfloat16* vT    = qkvb  + (size_t)MEXT * 2304;       // 4*12*64*512
    __hip_bfloat16* vrT   = vT    + (size_t)B_ * NH_ * 64 * 512; // 12*64*256
    __hip_bfloat16* WtQ   = vrT   + (size_t)NH_ * 64 * 256;    // 2304*768
    __hip_bfloat16* WtO   = WtQ   + (size_t)2304 * H_;         // 768*768
    __hip_bfloat16* WtW1  = WtO   + (size_t)H_ * H_;           // 3072*768
    __hip_bfloat16* WtW2  = WtW1  + (size_t)M_ * H_;           // 768*3072
    __hip_bfloat16* h1b   = WtW2  + (size_t)H_ * M_;           // 2048*3072

    float* spill = (float*)qkvb;   // split-K partials alias qkvb/vT (dead after attn)

    dim3 blk(256);
    dim3 blk512(512);

    embed_ln_kernel<<<ROWS, blk, 0, stream>>>(tok, seg, temb, semb, esc, ebi, x, xb);

    for (int l = 0; l < NL_; l++) {
        const float* wq = Wq + (size_t)l * H_ * H_;
        const float* wk = Wk + (size_t)l * H_ * H_;
        const float* wv = Wv + (size_t)l * H_ * H_;
        const float* wo = Wo + (size_t)l * H_ * H_;
        const float* w1 = W1 + (size_t)l * H_ * M_;
        const float* w2 = W2 + (size_t)l * M_ * H_;

        pack_layer_kernel<<<dim3(96, 24, 7), blk, 0, stream>>>(
            wq, wk, wv, wo, w1, w2,
            bq + (size_t)l * H_, bk + (size_t)l * H_, bv + (size_t)l * H_,
            relpos + (size_t)l * NR_ * H_,
            WtQ, WtO, WtW1, WtW2, qkvbias, xb + (size_t)ROWS * H_);

        // merged QKV + rel projection: [MEXT][768] @ [2304][768]^T -> qkvb [MEXT][2304]
        gemm_bf16_kernel<<<dim3(36, 18), blk512, 0, stream>>>(xb, WtQ, qkvbias, nullptr, qkvb, nullptr, 0,
                                                              MEXT, 2304, H_, 0, H_);
        transpose_vvr_kernel<<<dim3(36, 12), blk, 0, stream>>>(qkvb, vT, vrT);

        attn_kernel<<<dim3(768), blk, 0, stream>>>(qkvb, vT, vrT, maskp, ctxb);

        // O projection: split-K x2 (768 -> 2x384); bias added in add_ln
        gemm_bf16_kernel<<<dim3(12, 16, 2), blk512, 0, stream>>>(ctxb, WtO, nullptr, y, nullptr, spill, NX,
                                                                 ROWS, H_, H_, 0, 384);
        add_ln_kernel<<<ROWS, blk, 0, stream>>>(x, y, spill, nullptr, bo + (size_t)l * H_,
                                                ln1s + (size_t)l * H_, ln1b + (size_t)l * H_, x2, x2b);

        // MLP
        gemm_bf16_kernel<<<dim3(48, 16), blk512, 0, stream>>>(x2b, WtW1, b1 + (size_t)l * M_, nullptr, h1b, nullptr, 0,
                                                              ROWS, M_, H_, 1, H_);
        gemm_bf16_kernel<<<dim3(12, 16, 3), blk512, 0, stream>>>(h1b, WtW2, nullptr, y, nullptr, spill, NX,
                                                                 ROWS, H_, M_, 0, 1024);

        float* outp = (l == NL_ - 1) ? (float*)d_out : x;
        __hip_bfloat16* outbp = (l == NL_ - 1) ? nullptr : xb;
        add_ln_kernel<<<ROWS, blk, 0, stream>>>(x2, y, spill, spill + NX, b2 + (size_t)l * H_,
                                                ln2s + (size_t)l * H_, ln2b + (size_t)l * H_, outp, outbp);
    }
}